// Round 26
// baseline (134.188 us; speedup 1.0000x reference)
//
#include <hip/hip_runtime.h>
#include <hip/hip_bf16.h>

#define N_NODES 50000
#define N_EDGES 600000
#define DIM_IN  128
#define DIM_OUT 256
#define EPS_BN  1e-5f
#define PAD_DEG 60      // padded CSR bucket size; P(Poisson(12) >= 60) ~ 1e-26
#define NBLK_Z    196   // zero blocks (ceil(50000/256))
#define NBLK_CVTX 3125  // 50000*128/8/256
#define NBLK_WT   64    // 2 matrices x 4 k-tiles x 8 n-tiles (32x32 LDS transpose)
#define NREP 16         // replicated stat accumulators (contention spread)

// ---- ws layout (float offsets) ----
// xb    : [0, 3.2M)        x as bf16 (6.4M ushort)
// CSR   : [3.2M, 6.4M)     int scratch: cnt[50000], srcs[50000*60] (padded buckets)
// P     : [6.4M, 19.2M)    12.8M uint pairs {og_bf16 | sc_bf16<<16}
// stats : base 19.2M: acc16[16][512], flag, pad, Wt bf16
#define OFF_XB    0
#define OFF_CSR   3200000
#define OFF_P     6400000
#define OFF_STATS 19200000

typedef __attribute__((ext_vector_type(8))) short short8;
typedef __attribute__((ext_vector_type(8))) unsigned int uint8v;
typedef __attribute__((ext_vector_type(4))) unsigned int uint4v;
typedef __attribute__((ext_vector_type(2))) unsigned int uint2v;
typedef __attribute__((ext_vector_type(4))) float float4v;

__device__ __forceinline__ unsigned short f2bf(float f) {
    unsigned int x = __builtin_bit_cast(unsigned int, f);
    unsigned int r = (x + 0x7fffu + ((x >> 16) & 1u)) >> 16;   // RNE
    return (unsigned short)r;
}
__device__ __forceinline__ float bf2f(unsigned short b) {
    unsigned int u = ((unsigned int)b) << 16;
    return __builtin_bit_cast(float, u);
}

__device__ __forceinline__ int load_edge(const void* edges, int idx, int flag) {
    return flag ? (int)((const long long*)edges)[idx] : ((const int*)edges)[idx];
}

// Prep: blocks [0,NBLK_Z) zero cnt+acc16 (block 0 also runs edge-dtype detect);
// next NBLK_CVTX convert x->xb; last NBLK_WT transpose+convert weights (32x32 LDS).
__global__ __launch_bounds__(256) void k_prep(const unsigned int* __restrict__ e,
                                              int* __restrict__ cnt,
                                              float* __restrict__ acc16,
                                              int* __restrict__ flag,
                                              const float* __restrict__ x,
                                              const float* __restrict__ Wg,
                                              const float* __restrict__ Ws,
                                              unsigned short* __restrict__ xb,
                                              unsigned short* __restrict__ wtg,
                                              unsigned short* __restrict__ wts) {
    int bid = blockIdx.x;
    if (bid < NBLK_Z) {
        int gid = bid * 256 + threadIdx.x;
        if (gid < N_NODES) cnt[gid] = 0;
        if (gid < NREP * 512) acc16[gid] = 0.f;
        if (bid == 0) {
            __shared__ int nz;
            if (threadIdx.x == 0) nz = 0;
            __syncthreads();
            int c = 0;
            for (int i = threadIdx.x; i < 1024; i += 256) c += (e[2 * i + 1] != 0u);
            if (c) atomicAdd(&nz, c);
            __syncthreads();
            if (threadIdx.x == 0) *flag = (nz == 0) ? 1 : 0;
        }
    } else if (bid < NBLK_Z + NBLK_CVTX) {
        int b2 = bid - NBLK_Z;
        size_t i = ((size_t)b2 * 256 + threadIdx.x) * 8;
        float4 a = *(const float4*)(x + i);
        float4 b = *(const float4*)(x + i + 4);
        short8 s;
        s[0]=(short)f2bf(a.x); s[1]=(short)f2bf(a.y); s[2]=(short)f2bf(a.z); s[3]=(short)f2bf(a.w);
        s[4]=(short)f2bf(b.x); s[5]=(short)f2bf(b.y); s[6]=(short)f2bf(b.z); s[7]=(short)f2bf(b.w);
        *(short8*)(xb + i) = s;
    } else {
        int wb = bid - NBLK_Z - NBLK_CVTX;      // 0..63
        const float* W = (wb & 1) ? Ws : Wg;
        unsigned short* O = (wb & 1) ? wts : wtg;
        int kt = (wb >> 1) & 3;                 // k-tile 0..3
        int nt = wb >> 3;                       // n-tile 0..7
        __shared__ float tile[32][33];
        int tr = threadIdx.x >> 3;              // 0..31
        int tc = (threadIdx.x & 7) * 4;         // 0..28 step 4
        float4 v = *(const float4*)(W + (size_t)(kt * 32 + tr) * DIM_OUT + nt * 32 + tc);
        tile[tr][tc] = v.x; tile[tr][tc + 1] = v.y; tile[tr][tc + 2] = v.z; tile[tr][tc + 3] = v.w;
        __syncthreads();
        uint2v o;
        o[0] = ((unsigned int)f2bf(tile[tc][tr]))     | (((unsigned int)f2bf(tile[tc + 1][tr])) << 16);
        o[1] = ((unsigned int)f2bf(tile[tc + 2][tr])) | (((unsigned int)f2bf(tile[tc + 3][tr])) << 16);
        *(uint2v*)(O + (size_t)(nt * 32 + tr) * DIM_IN + kt * 32 + tc) = o;
    }
}

// Padded-bucket CSR fill: slot = atomicAdd(cnt[d]); srcs[d*PAD_DEG+slot] = s.
__global__ __launch_bounds__(256) void k_fill(const void* __restrict__ edges,
                                              int* __restrict__ cnt,
                                              int* __restrict__ srcs,
                                              const int* __restrict__ flag) {
    int e = blockIdx.x * 256 + threadIdx.x;
    if (e >= N_EDGES) return;
    int f = *flag;
    int s = load_edge(edges, e, f);
    int d = load_edge(edges, N_EDGES + e, f);
    int slot = atomicAdd(&cnt[d], 1);
    if (slot < PAD_DEG) srcs[d * PAD_DEG + slot] = s;
}

// Dual MFMA GEMM with FUSED GATHER staging + fused column stats.
// 512 thr = 8 waves, tile M=32 x N=256. Quarter-wave gather; 4/2/1 MLP ladder.
// C-write staged through LDS (Ps, row stride 260) for full-line coalesced stores
// (the direct per-lane store pattern wrote 64B half-lines -> ~2x write amplification).
__global__ __launch_bounds__(512) void k_gemm_mfma(const unsigned short* __restrict__ xb,
                                                   const int* __restrict__ cnt,
                                                   const int* __restrict__ srcs,
                                                   const unsigned short* __restrict__ wtg,
                                                   const unsigned short* __restrict__ wts,
                                                   const float* __restrict__ bg,
                                                   const float* __restrict__ bs,
                                                   unsigned int* __restrict__ P,
                                                   float* __restrict__ acc16) {
    __shared__ short As[32 * 136];
    __shared__ short Xs[32 * 136];
    __shared__ unsigned int Ps[32 * 260];   // padded stride: 2-way bank alias only
    const int r0 = blockIdx.x * 32;
    const int t = threadIdx.x;
    const int lane = t & 63;
    const int w = t >> 6;              // 0..7

    // ---- Xs staging: thread t -> row t>>4, 16B chunk t&15 ----
    {
        int row = t >> 4;
        int ch  = (t & 15) * 8;
        int grow = r0 + row;
        if (grow < N_NODES) {
            *(short8*)&Xs[row * 136 + ch] = *(const short8*)(xb + (size_t)grow * DIM_IN + ch);
        } else {
            short8 z = {0,0,0,0,0,0,0,0};
            *(short8*)&Xs[row * 136 + ch] = z;
        }
    }

    // ---- As staging = fused gather: quarter-wave per row, 4 rows concurrent ----
    {
        const int q  = lane >> 4;          // quarter 0..3
        const int ql = lane & 15;          // lane within quarter
        const int qbase = q * 16;
        const int lrow = w * 4 + q;
        const int row  = r0 + lrow;
        float a[8] = {0.f, 0.f, 0.f, 0.f, 0.f, 0.f, 0.f, 0.f};
        if (row < N_NODES) {
            int b = row * PAD_DEG;
            int e = b + min(cnt[row], PAD_DEG);
            for (int i0 = b; i0 < e; i0 += 16) {
                int cntc = min(16, e - i0);
                int si = (i0 + ql < e) ? srcs[i0 + ql] : 0;
                int j = 0;
                for (; j + 4 <= cntc; j += 4) {
                    uint4v u[4];
                    #pragma unroll
                    for (int k = 0; k < 4; ++k) {
                        int s = __shfl(si, qbase + j + k, 64);
                        u[k] = *(const uint4v*)(xb + (size_t)s * DIM_IN + ql * 8);
                    }
                    #pragma unroll
                    for (int k = 0; k < 4; ++k) {
                        #pragma unroll
                        for (int m = 0; m < 4; ++m) {
                            a[2 * m]     += __builtin_bit_cast(float, u[k][m] << 16);
                            a[2 * m + 1] += __builtin_bit_cast(float, u[k][m] & 0xffff0000u);
                        }
                    }
                }
                for (; j + 2 <= cntc; j += 2) {
                    uint4v u[2];
                    #pragma unroll
                    for (int k = 0; k < 2; ++k) {
                        int s = __shfl(si, qbase + j + k, 64);
                        u[k] = *(const uint4v*)(xb + (size_t)s * DIM_IN + ql * 8);
                    }
                    #pragma unroll
                    for (int k = 0; k < 2; ++k) {
                        #pragma unroll
                        for (int m = 0; m < 4; ++m) {
                            a[2 * m]     += __builtin_bit_cast(float, u[k][m] << 16);
                            a[2 * m + 1] += __builtin_bit_cast(float, u[k][m] & 0xffff0000u);
                        }
                    }
                }
                for (; j < cntc; ++j) {
                    int s = __shfl(si, qbase + j, 64);
                    uint4v u = *(const uint4v*)(xb + (size_t)s * DIM_IN + ql * 8);
                    #pragma unroll
                    for (int m = 0; m < 4; ++m) {
                        a[2 * m]     += __builtin_bit_cast(float, u[m] << 16);
                        a[2 * m + 1] += __builtin_bit_cast(float, u[m] & 0xffff0000u);
                    }
                }
            }
        }
        uint4v o;
        #pragma unroll
        for (int m = 0; m < 4; ++m)
            o[m] = ((unsigned int)f2bf(a[2 * m])) | (((unsigned int)f2bf(a[2 * m + 1])) << 16);
        *(uint4v*)&As[lrow * 136 + ql * 8] = o;
    }
    __syncthreads();

    const int c0 = w * 32;
    const int lc = lane & 15;
    const int lg = lane >> 4;
    const int kg = lg * 8;

    float4v accg[2][2], accs[2][2];
    #pragma unroll
    for (int ct = 0; ct < 2; ++ct) {
        int col = c0 + ct * 16 + lc;
        float bgv = bg[col], bsv = bs[col];
        float4v vg = {bgv, bgv, bgv, bgv};
        float4v vs = {bsv, bsv, bsv, bsv};
        accg[0][ct] = vg; accg[1][ct] = vg;
        accs[0][ct] = vs; accs[1][ct] = vs;
    }

    #pragma unroll
    for (int ks = 0; ks < 4; ++ks) {
        short8 afa[2], afx[2];
        #pragma unroll
        for (int rt = 0; rt < 2; ++rt) {
            int off = (rt * 16 + lc) * 136 + ks * 32 + kg;
            afa[rt] = *(const short8*)&As[off];
            afx[rt] = *(const short8*)&Xs[off];
        }
        #pragma unroll
        for (int ct = 0; ct < 2; ++ct) {
            int col = c0 + ct * 16 + lc;
            size_t woff = (size_t)col * DIM_IN + ks * 32 + kg;
            short8 bfg = *(const short8*)(wtg + woff);
            short8 bfs = *(const short8*)(wts + woff);
            #pragma unroll
            for (int rt = 0; rt < 2; ++rt) {
                accg[rt][ct] = __builtin_amdgcn_mfma_f32_16x16x32_bf16(afa[rt], bfg, accg[rt][ct], 0, 0, 0);
                accs[rt][ct] = __builtin_amdgcn_mfma_f32_16x16x32_bf16(afx[rt], bfs, accs[rt][ct], 0, 0, 0);
            }
        }
    }

    // ---- stage packed pairs to LDS: row = rt*16 + lg*4 + r, col = ct*16 + lc ----
    #pragma unroll
    for (int rt = 0; rt < 2; ++rt) {
        #pragma unroll
        for (int r = 0; r < 4; ++r) {
            int lr = rt * 16 + lg * 4 + r;
            #pragma unroll
            for (int ct = 0; ct < 2; ++ct) {
                int col = c0 + ct * 16 + lc;
                unsigned int pv = (unsigned int)f2bf(accg[rt][ct][r])
                                | (((unsigned int)f2bf(accs[rt][ct][r])) << 16);
                Ps[lr * 260 + col] = pv;
            }
        }
    }

    // ---- fused column stats on og, replica blockIdx&(NREP-1) ----
    float* myacc = acc16 + (blockIdx.x & (NREP - 1)) * 512;
    #pragma unroll
    for (int ct = 0; ct < 2; ++ct) {
        float s = 0.f, q = 0.f;
        #pragma unroll
        for (int rt = 0; rt < 2; ++rt) {
            #pragma unroll
            for (int r = 0; r < 4; ++r) {
                int row = r0 + rt * 16 + lg * 4 + r;
                if (row < N_NODES) {
                    float v = accg[rt][ct][r];
                    s += v;
                    q += v * v;
                }
            }
        }
        s += __shfl_xor(s, 16, 64);
        s += __shfl_xor(s, 32, 64);
        q += __shfl_xor(q, 16, 64);
        q += __shfl_xor(q, 32, 64);
        if (lg == 0) {
            int col = c0 + ct * 16 + lc;
            atomicAdd(&myacc[col], s);
            atomicAdd(&myacc[256 + col], q);
        }
    }
    __syncthreads();

    // ---- coalesced P write: thread t -> row t>>4, 64B chunk (t&15)*16 uints ----
    {
        int row = t >> 4;                 // 0..31
        int cu  = (t & 15) * 16;          // uint offset within row
        int grow = r0 + row;
        if (grow < N_NODES) {
            uint4v* dst = (uint4v*)(P + (size_t)grow * DIM_OUT + cu);
            const unsigned int* src = &Ps[row * 260 + cu];
            dst[0] = *(const uint4v*)(src);
            dst[1] = *(const uint4v*)(src + 4);
            dst[2] = *(const uint4v*)(src + 8);
            dst[3] = *(const uint4v*)(src + 12);
        }
    }
}

// out = sc + elu(og*scale + shift), reading packed pairs P = og | sc<<16.
// BN params recomputed per-block from acc16 into LDS (cheap L2-broadcast).
// 16 elems/thread; fast exp; nontemporal stores.
__global__ __launch_bounds__(256) void k_final(const unsigned int* __restrict__ P,
                                               const float* __restrict__ acc16,
                                               const float* __restrict__ gamma,
                                               const float* __restrict__ beta,
                                               float* __restrict__ out) {
    __shared__ float s_scale[256], s_shift[256];
    {
        const int c = threadIdx.x;
        float S = 0.f, Q = 0.f;
        #pragma unroll
        for (int r = 0; r < NREP; ++r) {
            S += acc16[r * 512 + c];
            Q += acc16[r * 512 + 256 + c];
        }
        const float inv_n = 1.f / (float)N_NODES;
        float mean = S * inv_n;
        float var  = fmaxf(Q * inv_n - mean * mean, 0.f);
        float sc   = gamma[c] * rsqrtf(var + EPS_BN);
        s_scale[c] = sc;
        s_shift[c] = beta[c] - mean * sc;
    }
    __syncthreads();

    size_t i16 = ((size_t)blockIdx.x * 256 + threadIdx.x) * 16;
    int c0 = (int)(i16 & (DIM_OUT - 1));    // multiple of 16
    uint8v p0 = *(const uint8v*)(P + i16);
    uint8v p1 = *(const uint8v*)(P + i16 + 8);
    float4v sc4[4], sh4[4];
    #pragma unroll
    for (int j = 0; j < 4; ++j) {
        sc4[j] = *(const float4v*)(&s_scale[c0 + j * 4]);
        sh4[j] = *(const float4v*)(&s_shift[c0 + j * 4]);
    }
    float res[16];
    #pragma unroll
    for (int j = 0; j < 16; ++j) {
        unsigned int pv = (j < 8) ? p0[j] : p1[j - 8];
        float og = bf2f((unsigned short)(pv & 0xffffu));
        float sc = bf2f((unsigned short)(pv >> 16));
        float sl = sc4[j >> 2][j & 3];
        float sh = sh4[j >> 2][j & 3];
        float b = og * sl + sh;
        float e = (b > 0.f) ? b : (__expf(b) - 1.f);
        res[j] = sc + e;
    }
    #pragma unroll
    for (int j = 0; j < 4; ++j) {
        float4v o = {res[4 * j], res[4 * j + 1], res[4 * j + 2], res[4 * j + 3]};
        __builtin_nontemporal_store(o, (float4v*)(out + i16 + 4 * j));
    }
}

extern "C" void kernel_launch(void* const* d_in, const int* in_sizes, int n_in,
                              void* d_out, int out_size, void* d_ws, size_t ws_size,
                              hipStream_t stream) {
    const float* x     = (const float*)d_in[0];
    const void*  edges = d_in[1];
    const float* Wg    = (const float*)d_in[2];
    const float* bg    = (const float*)d_in[3];
    const float* gamma = (const float*)d_in[4];
    const float* beta  = (const float*)d_in[5];
    const float* Wsc   = (const float*)d_in[6];
    const float* bsc   = (const float*)d_in[7];

    float* ws    = (float*)d_ws;
    unsigned short* xb   = (unsigned short*)(ws + OFF_XB);
    unsigned int*   P    = (unsigned int*)(ws + OFF_P);
    float* acc16 = ws + OFF_STATS;                 // 16*512 f32
    int*   flag  = (int*)(acc16 + NREP * 512);
    unsigned short* wtg = (unsigned short*)(flag + 16);   // 256*128 bf16
    unsigned short* wts = wtg + 256 * 128;
    float* out   = (float*)d_out;

    // Padded CSR: cnt[50000], srcs[50000*60] = 12.2 MB in the 12.8 MB CSR region
    int* ib   = (int*)(ws + OFF_CSR);
    int* cnt  = ib;
    int* srcs = ib + 50000;

    k_prep<<<NBLK_Z + NBLK_CVTX + NBLK_WT, 256, 0, stream>>>((const unsigned int*)edges, cnt, acc16, flag,
                                                             x, Wg, Wsc, xb, wtg, wts);
    k_fill<<<(N_EDGES + 255) / 256, 256, 0, stream>>>(edges, cnt, srcs, flag);
    k_gemm_mfma<<<(N_NODES + 31) / 32, 512, 0, stream>>>(xb, cnt, srcs, wtg, wts, bg, bsc, P, acc16);
    k_final<<<(N_NODES * DIM_OUT / 16) / 256, 256, 0, stream>>>(P, acc16, gamma, beta, out);
}

// Round 29
// 124.217 us; speedup vs baseline: 1.0803x; 1.0803x over previous
//
#include <hip/hip_runtime.h>
#include <hip/hip_bf16.h>

#define N_NODES 50000
#define N_EDGES 600000
#define DIM_IN  128
#define DIM_OUT 256
#define EPS_BN  1e-5f
#define PAD_DEG 60      // padded CSR bucket size; P(Poisson(12) >= 60) ~ 1e-26
#define NBLK_Z    196   // zero/init blocks (ceil(50000/256))
#define NBLK_FILL 2344  // ceil(600000/256)
#define NBLK_CVTX 3125  // 50000*128/8/256
#define NBLK_WT   64    // 2 matrices x 4 k-tiles x 8 n-tiles (32x32 LDS transpose)
#define NREP 16         // replicated stat accumulators (contention spread)

// ---- ws layout (float offsets) ----
// xb    : [0, 3.2M)        x as bf16 (6.4M ushort)
// CSR   : [3.2M, 6.4M)     int scratch: cnt[50000], srcs[50000*60] (padded buckets)
// P     : [6.4M, 19.2M)    12.8M uint pairs {og_bf16 | sc_bf16<<16}
// stats : base 19.2M: acc16[16][512], flag, pad, Wt bf16
#define OFF_XB    0
#define OFF_CSR   3200000
#define OFF_P     6400000
#define OFF_STATS 19200000

typedef __attribute__((ext_vector_type(8))) short short8;
typedef __attribute__((ext_vector_type(8))) unsigned int uint8v;
typedef __attribute__((ext_vector_type(4))) unsigned int uint4v;
typedef __attribute__((ext_vector_type(2))) unsigned int uint2v;
typedef __attribute__((ext_vector_type(4))) float float4v;

__device__ __forceinline__ unsigned short f2bf(float f) {
    unsigned int x = __builtin_bit_cast(unsigned int, f);
    unsigned int r = (x + 0x7fffu + ((x >> 16) & 1u)) >> 16;   // RNE
    return (unsigned short)r;
}
__device__ __forceinline__ float bf2f(unsigned short b) {
    unsigned int u = ((unsigned int)b) << 16;
    return __builtin_bit_cast(float, u);
}

__device__ __forceinline__ int load_edge(const void* edges, int idx, int flag) {
    return flag ? (int)((const long long*)edges)[idx] : ((const int*)edges)[idx];
}

// Init: zero cnt + acc16; block 0 runs the int64/int32 edge-dtype detect. (~3us)
__global__ __launch_bounds__(256) void k_init(const unsigned int* __restrict__ e,
                                              int* __restrict__ cnt,
                                              float* __restrict__ acc16,
                                              int* __restrict__ flag) {
    int gid = blockIdx.x * 256 + threadIdx.x;
    if (gid < N_NODES) cnt[gid] = 0;
    if (gid < NREP * 512) acc16[gid] = 0.f;
    if (blockIdx.x == 0) {
        __shared__ int nz;
        if (threadIdx.x == 0) nz = 0;
        __syncthreads();
        int c = 0;
        for (int i = threadIdx.x; i < 1024; i += 256) c += (e[2 * i + 1] != 0u);
        if (c) atomicAdd(&nz, c);
        __syncthreads();
        if (threadIdx.x == 0) *flag = (nz == 0) ? 1 : 0;
    }
}

// Work: blocks [0,NBLK_FILL) do the padded-bucket CSR fill (atomic-latency-bound,
// hides under the cvt blocks' BW phase); next NBLK_CVTX convert x->xb; last
// NBLK_WT transpose+convert the weight matrices via 32x32 LDS tiles.
__global__ __launch_bounds__(256) void k_work(const void* __restrict__ edges,
                                              int* __restrict__ cnt,
                                              int* __restrict__ srcs,
                                              const int* __restrict__ flag,
                                              const float* __restrict__ x,
                                              const float* __restrict__ Wg,
                                              const float* __restrict__ Ws,
                                              unsigned short* __restrict__ xb,
                                              unsigned short* __restrict__ wtg,
                                              unsigned short* __restrict__ wts) {
    int bid = blockIdx.x;
    if (bid < NBLK_FILL) {
        int e = bid * 256 + threadIdx.x;
        if (e >= N_EDGES) return;
        int f = *flag;
        int s = load_edge(edges, e, f);
        int d = load_edge(edges, N_EDGES + e, f);
        int slot = atomicAdd(&cnt[d], 1);
        if (slot < PAD_DEG) srcs[d * PAD_DEG + slot] = s;
    } else if (bid < NBLK_FILL + NBLK_CVTX) {
        int b2 = bid - NBLK_FILL;
        size_t i = ((size_t)b2 * 256 + threadIdx.x) * 8;
        float4 a = *(const float4*)(x + i);
        float4 b = *(const float4*)(x + i + 4);
        short8 s;
        s[0]=(short)f2bf(a.x); s[1]=(short)f2bf(a.y); s[2]=(short)f2bf(a.z); s[3]=(short)f2bf(a.w);
        s[4]=(short)f2bf(b.x); s[5]=(short)f2bf(b.y); s[6]=(short)f2bf(b.z); s[7]=(short)f2bf(b.w);
        *(short8*)(xb + i) = s;
    } else {
        int wb = bid - NBLK_FILL - NBLK_CVTX;   // 0..63
        const float* W = (wb & 1) ? Ws : Wg;
        unsigned short* O = (wb & 1) ? wts : wtg;
        int kt = (wb >> 1) & 3;                 // k-tile 0..3
        int nt = wb >> 3;                       // n-tile 0..7
        __shared__ float tile[32][33];
        int tr = threadIdx.x >> 3;              // 0..31
        int tc = (threadIdx.x & 7) * 4;         // 0..28 step 4
        float4 v = *(const float4*)(W + (size_t)(kt * 32 + tr) * DIM_OUT + nt * 32 + tc);
        tile[tr][tc] = v.x; tile[tr][tc + 1] = v.y; tile[tr][tc + 2] = v.z; tile[tr][tc + 3] = v.w;
        __syncthreads();
        uint2v o;
        o[0] = ((unsigned int)f2bf(tile[tc][tr]))     | (((unsigned int)f2bf(tile[tc + 1][tr])) << 16);
        o[1] = ((unsigned int)f2bf(tile[tc + 2][tr])) | (((unsigned int)f2bf(tile[tc + 3][tr])) << 16);
        *(uint2v*)(O + (size_t)(nt * 32 + tr) * DIM_IN + kt * 32 + tc) = o;
    }
}

// Dual MFMA GEMM with FUSED GATHER staging + fused column stats (R25 version:
// direct P stores — LDS-staged stores regressed, WRITE_SIZE proved no amplification).
// 512 thr = 8 waves, tile M=32 x N=256. Quarter-wave gather; 4/2/1 MLP ladder.
__global__ __launch_bounds__(512) void k_gemm_mfma(const unsigned short* __restrict__ xb,
                                                   const int* __restrict__ cnt,
                                                   const int* __restrict__ srcs,
                                                   const unsigned short* __restrict__ wtg,
                                                   const unsigned short* __restrict__ wts,
                                                   const float* __restrict__ bg,
                                                   const float* __restrict__ bs,
                                                   unsigned int* __restrict__ P,
                                                   float* __restrict__ acc16) {
    __shared__ short As[32 * 136];
    __shared__ short Xs[32 * 136];
    const int r0 = blockIdx.x * 32;
    const int t = threadIdx.x;
    const int lane = t & 63;
    const int w = t >> 6;              // 0..7

    // ---- Xs staging: thread t -> row t>>4, 16B chunk t&15 ----
    {
        int row = t >> 4;
        int ch  = (t & 15) * 8;
        int grow = r0 + row;
        if (grow < N_NODES) {
            *(short8*)&Xs[row * 136 + ch] = *(const short8*)(xb + (size_t)grow * DIM_IN + ch);
        } else {
            short8 z = {0,0,0,0,0,0,0,0};
            *(short8*)&Xs[row * 136 + ch] = z;
        }
    }

    // ---- As staging = fused gather: quarter-wave per row, 4 rows concurrent ----
    {
        const int q  = lane >> 4;          // quarter 0..3
        const int ql = lane & 15;          // lane within quarter
        const int qbase = q * 16;
        const int lrow = w * 4 + q;
        const int row  = r0 + lrow;
        float a[8] = {0.f, 0.f, 0.f, 0.f, 0.f, 0.f, 0.f, 0.f};
        if (row < N_NODES) {
            int b = row * PAD_DEG;
            int e = b + min(cnt[row], PAD_DEG);
            for (int i0 = b; i0 < e; i0 += 16) {
                int cntc = min(16, e - i0);
                int si = (i0 + ql < e) ? srcs[i0 + ql] : 0;
                int j = 0;
                for (; j + 4 <= cntc; j += 4) {
                    uint4v u[4];
                    #pragma unroll
                    for (int k = 0; k < 4; ++k) {
                        int s = __shfl(si, qbase + j + k, 64);
                        u[k] = *(const uint4v*)(xb + (size_t)s * DIM_IN + ql * 8);
                    }
                    #pragma unroll
                    for (int k = 0; k < 4; ++k) {
                        #pragma unroll
                        for (int m = 0; m < 4; ++m) {
                            a[2 * m]     += __builtin_bit_cast(float, u[k][m] << 16);
                            a[2 * m + 1] += __builtin_bit_cast(float, u[k][m] & 0xffff0000u);
                        }
                    }
                }
                for (; j + 2 <= cntc; j += 2) {
                    uint4v u[2];
                    #pragma unroll
                    for (int k = 0; k < 2; ++k) {
                        int s = __shfl(si, qbase + j + k, 64);
                        u[k] = *(const uint4v*)(xb + (size_t)s * DIM_IN + ql * 8);
                    }
                    #pragma unroll
                    for (int k = 0; k < 2; ++k) {
                        #pragma unroll
                        for (int m = 0; m < 4; ++m) {
                            a[2 * m]     += __builtin_bit_cast(float, u[k][m] << 16);
                            a[2 * m + 1] += __builtin_bit_cast(float, u[k][m] & 0xffff0000u);
                        }
                    }
                }
                for (; j < cntc; ++j) {
                    int s = __shfl(si, qbase + j, 64);
                    uint4v u = *(const uint4v*)(xb + (size_t)s * DIM_IN + ql * 8);
                    #pragma unroll
                    for (int m = 0; m < 4; ++m) {
                        a[2 * m]     += __builtin_bit_cast(float, u[m] << 16);
                        a[2 * m + 1] += __builtin_bit_cast(float, u[m] & 0xffff0000u);
                    }
                }
            }
        }
        uint4v o;
        #pragma unroll
        for (int m = 0; m < 4; ++m)
            o[m] = ((unsigned int)f2bf(a[2 * m])) | (((unsigned int)f2bf(a[2 * m + 1])) << 16);
        *(uint4v*)&As[lrow * 136 + ql * 8] = o;
    }
    __syncthreads();

    const int c0 = w * 32;
    const int lc = lane & 15;
    const int lg = lane >> 4;
    const int kg = lg * 8;

    float4v accg[2][2], accs[2][2];
    #pragma unroll
    for (int ct = 0; ct < 2; ++ct) {
        int col = c0 + ct * 16 + lc;
        float bgv = bg[col], bsv = bs[col];
        float4v vg = {bgv, bgv, bgv, bgv};
        float4v vs = {bsv, bsv, bsv, bsv};
        accg[0][ct] = vg; accg[1][ct] = vg;
        accs[0][ct] = vs; accs[1][ct] = vs;
    }

    #pragma unroll
    for (int ks = 0; ks < 4; ++ks) {
        short8 afa[2], afx[2];
        #pragma unroll
        for (int rt = 0; rt < 2; ++rt) {
            int off = (rt * 16 + lc) * 136 + ks * 32 + kg;
            afa[rt] = *(const short8*)&As[off];
            afx[rt] = *(const short8*)&Xs[off];
        }
        #pragma unroll
        for (int ct = 0; ct < 2; ++ct) {
            int col = c0 + ct * 16 + lc;
            size_t woff = (size_t)col * DIM_IN + ks * 32 + kg;
            short8 bfg = *(const short8*)(wtg + woff);
            short8 bfs = *(const short8*)(wts + woff);
            #pragma unroll
            for (int rt = 0; rt < 2; ++rt) {
                accg[rt][ct] = __builtin_amdgcn_mfma_f32_16x16x32_bf16(afa[rt], bfg, accg[rt][ct], 0, 0, 0);
                accs[rt][ct] = __builtin_amdgcn_mfma_f32_16x16x32_bf16(afx[rt], bfs, accs[rt][ct], 0, 0, 0);
            }
        }
    }

    // ---- store packed pairs: row = rt*16 + lg*4 + r, col = ct*16 + lc ----
    #pragma unroll
    for (int rt = 0; rt < 2; ++rt) {
        #pragma unroll
        for (int r = 0; r < 4; ++r) {
            int row = r0 + rt * 16 + lg * 4 + r;
            if (row < N_NODES) {
                #pragma unroll
                for (int ct = 0; ct < 2; ++ct) {
                    int col = c0 + ct * 16 + lc;
                    unsigned int pv = (unsigned int)f2bf(accg[rt][ct][r])
                                    | (((unsigned int)f2bf(accs[rt][ct][r])) << 16);
                    P[(size_t)row * DIM_OUT + col] = pv;
                }
            }
        }
    }

    // ---- fused column stats on og, replica blockIdx&(NREP-1) ----
    float* myacc = acc16 + (blockIdx.x & (NREP - 1)) * 512;
    #pragma unroll
    for (int ct = 0; ct < 2; ++ct) {
        float s = 0.f, q = 0.f;
        #pragma unroll
        for (int rt = 0; rt < 2; ++rt) {
            #pragma unroll
            for (int r = 0; r < 4; ++r) {
                int row = r0 + rt * 16 + lg * 4 + r;
                if (row < N_NODES) {
                    float v = accg[rt][ct][r];
                    s += v;
                    q += v * v;
                }
            }
        }
        s += __shfl_xor(s, 16, 64);
        s += __shfl_xor(s, 32, 64);
        q += __shfl_xor(q, 16, 64);
        q += __shfl_xor(q, 32, 64);
        if (lg == 0) {
            int col = c0 + ct * 16 + lc;
            atomicAdd(&myacc[col], s);
            atomicAdd(&myacc[256 + col], q);
        }
    }
}

// out = sc + elu(og*scale + shift), reading packed pairs P = og | sc<<16.
// BN params recomputed per-block from acc16 into LDS (cheap L2-broadcast).
// 16 elems/thread; fast exp; nontemporal stores.
__global__ __launch_bounds__(256) void k_final(const unsigned int* __restrict__ P,
                                               const float* __restrict__ acc16,
                                               const float* __restrict__ gamma,
                                               const float* __restrict__ beta,
                                               float* __restrict__ out) {
    __shared__ float s_scale[256], s_shift[256];
    {
        const int c = threadIdx.x;
        float S = 0.f, Q = 0.f;
        #pragma unroll
        for (int r = 0; r < NREP; ++r) {
            S += acc16[r * 512 + c];
            Q += acc16[r * 512 + 256 + c];
        }
        const float inv_n = 1.f / (float)N_NODES;
        float mean = S * inv_n;
        float var  = fmaxf(Q * inv_n - mean * mean, 0.f);
        float sc   = gamma[c] * rsqrtf(var + EPS_BN);
        s_scale[c] = sc;
        s_shift[c] = beta[c] - mean * sc;
    }
    __syncthreads();

    size_t i16 = ((size_t)blockIdx.x * 256 + threadIdx.x) * 16;
    int c0 = (int)(i16 & (DIM_OUT - 1));    // multiple of 16
    uint8v p0 = *(const uint8v*)(P + i16);
    uint8v p1 = *(const uint8v*)(P + i16 + 8);
    float4v sc4[4], sh4[4];
    #pragma unroll
    for (int j = 0; j < 4; ++j) {
        sc4[j] = *(const float4v*)(&s_scale[c0 + j * 4]);
        sh4[j] = *(const float4v*)(&s_shift[c0 + j * 4]);
    }
    float res[16];
    #pragma unroll
    for (int j = 0; j < 16; ++j) {
        unsigned int pv = (j < 8) ? p0[j] : p1[j - 8];
        float og = bf2f((unsigned short)(pv & 0xffffu));
        float sc = bf2f((unsigned short)(pv >> 16));
        float sl = sc4[j >> 2][j & 3];
        float sh = sh4[j >> 2][j & 3];
        float b = og * sl + sh;
        float e = (b > 0.f) ? b : (__expf(b) - 1.f);
        res[j] = sc + e;
    }
    #pragma unroll
    for (int j = 0; j < 4; ++j) {
        float4v o = {res[4 * j], res[4 * j + 1], res[4 * j + 2], res[4 * j + 3]};
        __builtin_nontemporal_store(o, (float4v*)(out + i16 + 4 * j));
    }
}

extern "C" void kernel_launch(void* const* d_in, const int* in_sizes, int n_in,
                              void* d_out, int out_size, void* d_ws, size_t ws_size,
                              hipStream_t stream) {
    const float* x     = (const float*)d_in[0];
    const void*  edges = d_in[1];
    const float* Wg    = (const float*)d_in[2];
    const float* bg    = (const float*)d_in[3];
    const float* gamma = (const float*)d_in[4];
    const float* beta  = (const float*)d_in[5];
    const float* Wsc   = (const float*)d_in[6];
    const float* bsc   = (const float*)d_in[7];

    float* ws    = (float*)d_ws;
    unsigned short* xb   = (unsigned short*)(ws + OFF_XB);
    unsigned int*   P    = (unsigned int*)(ws + OFF_P);
    float* acc16 = ws + OFF_STATS;                 // 16*512 f32
    int*   flag  = (int*)(acc16 + NREP * 512);
    unsigned short* wtg = (unsigned short*)(flag + 16);   // 256*128 bf16
    unsigned short* wts = wtg + 256 * 128;
    float* out   = (float*)d_out;

    // Padded CSR: cnt[50000], srcs[50000*60] = 12.2 MB in the 12.8 MB CSR region
    int* ib   = (int*)(ws + OFF_CSR);
    int* cnt  = ib;
    int* srcs = ib + 50000;

    k_init<<<NBLK_Z, 256, 0, stream>>>((const unsigned int*)edges, cnt, acc16, flag);
    k_work<<<NBLK_FILL + NBLK_CVTX + NBLK_WT, 256, 0, stream>>>(edges, cnt, srcs, flag,
                                                                x, Wg, Wsc, xb, wtg, wts);
    k_gemm_mfma<<<(N_NODES + 31) / 32, 512, 0, stream>>>(xb, cnt, srcs, wtg, wts, bg, bsc, P, acc16);
    k_final<<<(N_NODES * DIM_OUT / 16) / 256, 256, 0, stream>>>(P, acc16, gamma, beta, out);
}